// Round 1
// 246.414 us; speedup vs baseline: 1.2570x; 1.2570x over previous
//
#include <hip/hip_runtime.h>
#include <hip/hip_bf16.h>

#define CIN 384
#define PQ 1024
#define PKV 256
#define HEADS 6
#define DH 64
#define INNER 384
#define ATTN_SCALE 0.125f

typedef __hip_bfloat16 bf16;
typedef unsigned short ushort;
typedef __bf16 bf16x8 __attribute__((ext_vector_type(8)));
typedef float floatx4 __attribute__((ext_vector_type(4)));

__device__ __forceinline__ float b2f(bf16 v) { return __bfloat162float(v); }
__device__ __forceinline__ bf16 f2b(float v) { return __float2bfloat16(v); }
__device__ __forceinline__ ushort f2bu(float v) { bf16 h = __float2bfloat16(v); return *(ushort*)&h; }
__device__ __forceinline__ float ldf(const void* p, size_t i, int isbf) {
    return isbf ? __bfloat162float(((const bf16*)p)[i]) : ((const float*)p)[i];
}
// async global->LDS DMA, 16B per lane; LDS dest = uniform base + lane*16
__device__ __forceinline__ void dma16(const bf16* g, bf16* l) {
    __builtin_amdgcn_global_load_lds(
        (const __attribute__((address_space(1))) unsigned int*)g,
        (__attribute__((address_space(3))) unsigned int*)l, 16, 0, 0);
}

// ---------------- input dtype probe ----------------------------------------------
__global__ void detect_kernel(const unsigned int* __restrict__ x, int* __restrict__ flag) {
    if (threadIdx.x == 0 && blockIdx.x == 0) {
        int cnt = 0;
        for (int i = 0; i < 64; i++) {
            unsigned int e = (x[i] >> 7) & 0xFFu;
            if (e >= 100u && e <= 140u) cnt++;
        }
        *flag = (cnt >= 48) ? 1 : 0;
    }
}

// ---------------- weight convert: 3 segments -> contiguous bf16 ------------------
__global__ void wconv_kernel(const void* __restrict__ w0, const void* __restrict__ w1,
                             const void* __restrict__ w2, bf16* __restrict__ dst,
                             const int* __restrict__ flagp) {
    int isbf = *flagp;
    const int n0 = INNER * CIN, n1 = 2 * INNER * CIN, n2 = INNER * CIN;
    int i = blockIdx.x * 256 + threadIdx.x;
    int total = n0 + n1 + n2;
    for (; i < total; i += gridDim.x * 256) {
        float v;
        if (i < n0) v = ldf(w0, i, isbf);
        else if (i < n0 + n1) v = ldf(w1, i - n0, isbf);
        else v = ldf(w2, i - n0 - n1, isbf);
        dst[i] = f2b(v);
    }
}

// ---------------- depthwise 3x3 + BN -> Y^T [b][p][c] ----------------------------
// Vectorized rewrite: 16B global loads -> zero-padded LDS tile (RL=37 keeps the
// compute-phase ds_read at a free 2-way bank alias) -> sliding-window 3x3 in
// registers (3 LDS reads/output instead of 9) -> bf16 results restaged through
// LDS (union with input tile) -> uint4 coalesced stores.
template <int STRIDE, int HO, int WO>
__global__ __launch_bounds__(256) void dw_bn_kernel(
        const void* __restrict__ x, const void* __restrict__ wdw,
        const void* __restrict__ gamma, const void* __restrict__ beta,
        const void* __restrict__ mean, const void* __restrict__ var,
        bf16* __restrict__ yt, const int* __restrict__ flagp) {
    constexpr int IN_ROWS = (8 - 1) * STRIDE + 3;       // 10 or 17
    constexpr int RL = 37;                              // slab stride 370%32=18 -> 2-way
    constexpr int PT = 8 * WO;                          // output pixels per block
    constexpr unsigned XSZ = 32u * IN_ROWS * RL * 4;
    constexpr unsigned OSZ = (unsigned)PT * 40 * 2;
    __shared__ __align__(16) char smem[XSZ > OSZ ? XSZ : OSZ];
    float (*xin)[IN_ROWS][RL] = (float (*)[IN_ROWS][RL])smem;  // [cc][i][1+w], 0/33 zero pad
    ushort (*outt)[40] = (ushort (*)[40])smem;                 // [g*WO+wo][cc]

    int isbf = *flagp;
    int rg = blockIdx.x;
    int c0 = blockIdx.y * 32;
    int b  = blockIdx.z;
    int tid = threadIdx.x;
    int ri0 = rg * 8 * STRIDE - 1;

    // zero the halo columns (w=-1 at idx 0, w=32 at idx 33)
    for (int e = tid; e < 32 * IN_ROWS; e += 256) {
        int i = e % IN_ROWS, cc = e / IN_ROWS;
        xin[cc][i][0] = 0.f;
        xin[cc][i][33] = 0.f;
    }

    // stage: one 16B load (8 elems along w) per chunk; rows outside image -> zeros
    const int NCHUNK = 32 * IN_ROWS * 4;
    for (int ch = tid; ch < NCHUNK; ch += 256) {
        int wc = ch & 3;
        int t  = ch >> 2;
        int i  = t % IN_ROWS;
        int cc = t / IN_ROWS;
        int row = ri0 + i;
        float f[8];
        if (row >= 0 && row < 32) {
            size_t goff = ((size_t)(b * CIN + c0 + cc) * 32 + row) * 32 + wc * 8;
            if (isbf) {
                uint4 v = *(const uint4*)((const bf16*)x + goff);
                const ushort* u = (const ushort*)&v;
#pragma unroll
                for (int j = 0; j < 8; j++) f[j] = __uint_as_float((unsigned)u[j] << 16);
            } else {
                float4 v0 = *(const float4*)((const float*)x + goff);
                float4 v1 = *(const float4*)((const float*)x + goff + 4);
                f[0] = v0.x; f[1] = v0.y; f[2] = v0.z; f[3] = v0.w;
                f[4] = v1.x; f[5] = v1.y; f[6] = v1.z; f[7] = v1.w;
            }
        } else {
#pragma unroll
            for (int j = 0; j < 8; j++) f[j] = 0.f;
        }
        float* dst = &xin[cc][i][1 + wc * 8];
#pragma unroll
        for (int j = 0; j < 8; j++) dst[j] = f[j];
    }

    int cc = tid & 31;
    int g  = tid >> 5;
    int c  = c0 + cc;
    float w9[9];
#pragma unroll
    for (int k = 0; k < 9; k++) w9[k] = ldf(wdw, c * 9 + k, isbf);
    float inv  = ldf(gamma, c, isbf) * rsqrtf(ldf(var, c, isbf) + 1e-5f);
    float bias = ldf(beta, c, isbf) - ldf(mean, c, isbf) * inv;
    __syncthreads();

    // sliding-window 3x3: data w maps to LDS idx w+1, window for wo = idx wo*S..wo*S+2
    const float* xr0 = xin[cc][g * STRIDE + 0];
    const float* xr1 = xin[cc][g * STRIDE + 1];
    const float* xr2 = xin[cc][g * STRIDE + 2];
    float o[WO];
    if (STRIDE == 1) {
        float a0 = xr0[0], a1 = xr0[1];
        float b0 = xr1[0], b1 = xr1[1];
        float q0 = xr2[0], q1 = xr2[1];
#pragma unroll
        for (int wo = 0; wo < WO; wo++) {
            float a2 = xr0[wo + 2], b2 = xr1[wo + 2], q2 = xr2[wo + 2];
            float acc = w9[0] * a0 + w9[1] * a1 + w9[2] * a2
                      + w9[3] * b0 + w9[4] * b1 + w9[5] * b2
                      + w9[6] * q0 + w9[7] * q1 + w9[8] * q2;
            o[wo] = acc * inv + bias;
            a0 = a1; a1 = a2; b0 = b1; b1 = b2; q0 = q1; q1 = q2;
        }
    } else {
        float a0 = xr0[0], b0 = xr1[0], q0 = xr2[0];
#pragma unroll
        for (int wo = 0; wo < WO; wo++) {
            float a1 = xr0[2 * wo + 1], a2 = xr0[2 * wo + 2];
            float b1 = xr1[2 * wo + 1], b2 = xr1[2 * wo + 2];
            float q1 = xr2[2 * wo + 1], q2 = xr2[2 * wo + 2];
            float acc = w9[0] * a0 + w9[1] * a1 + w9[2] * a2
                      + w9[3] * b0 + w9[4] * b1 + w9[5] * b2
                      + w9[6] * q0 + w9[7] * q1 + w9[8] * q2;
            o[wo] = acc * inv + bias;
            a0 = a2; b0 = b2; q0 = q2;
        }
    }
    __syncthreads();  // all xin reads done -> safe to overwrite union with outputs

#pragma unroll
    for (int wo = 0; wo < WO; wo++) outt[g * WO + wo][cc] = f2bu(o[wo]);
    __syncthreads();

    // coalesced store: 16B per lane, 4 lanes cover the 32-channel slice of one pixel
    const size_t pbase = (size_t)b * (HO * WO) + (size_t)rg * 8 * WO;
    for (int chk = tid; chk < PT * 4; chk += 256) {
        int k = chk & 3, p = chk >> 2;
        uint4 v = *(const uint4*)&outt[p][k * 8];
        *(uint4*)(yt + (pbase + p) * CIN + c0 + k * 8) = v;
    }
}

// ---------------- MFMA pointwise GEMM, m97-style LDS-staged, double-buffered -----
// C^T[p][o] = sum_c Yt[b][p][c] * W[o][c]. 128x128 tile, BK=32.
// LDS rows 64B (4x16B chunks), chunk slot = c ^ (row&3) -> <=4-way on ds_read_b128.
template <int P, int MODE>
__global__ __launch_bounds__(256, 2) void mfma_pw(
        const bf16* __restrict__ wt, const bf16* __restrict__ yt,
        const void* __restrict__ bias, void* __restrict__ out0,
        bf16* __restrict__ out1, int O, const int* __restrict__ flagp) {
    __shared__ __align__(16) bf16 As[2][4096];  // 128 rows x 32 k
    __shared__ __align__(16) bf16 Bs[2][4096];
    int tid = threadIdx.x;
    int wave = tid >> 6, lane = tid & 63;
    int l15 = lane & 15, quad = lane >> 4;
    int wm = wave & 1, wn = wave >> 1;
    int b = blockIdx.z;
    int p0 = blockIdx.x * 128;
    int o0 = blockIdx.y * 128;

    const bf16* asrc = yt + ((size_t)b * P + p0) * CIN;
    const bf16* bsrc = wt + (size_t)o0 * CIN;

    // DMA staging: per wave 2 issues A + 2 issues B (16 rows x 32k each)
    int srow = (lane >> 2);           // 0..15 within issue
    int sc   = lane & 3;              // chunk slot
    auto stage = [&](int step, int buf) {
#pragma unroll
        for (int it = 0; it < 2; it++) {
            int row = wave * 32 + it * 16 + srow;
            int g = sc ^ (row & 3);
            size_t goff = (size_t)row * CIN + step * 32 + g * 8;
            dma16(asrc + goff, &As[buf][(wave * 2 + it) * 512]);
            dma16(bsrc + goff, &Bs[buf][(wave * 2 + it) * 512]);
        }
    };

    floatx4 acc[4][4];
#pragma unroll
    for (int pt = 0; pt < 4; pt++)
#pragma unroll
        for (int ot = 0; ot < 4; ot++) acc[pt][ot] = (floatx4){0.f, 0.f, 0.f, 0.f};

    stage(0, 0);
    __syncthreads();
    for (int s = 0; s < CIN / 32; s++) {
        int buf = s & 1;
        if (s < CIN / 32 - 1) stage(s + 1, buf ^ 1);
        bf16x8 af[4], bw[4];
        int slot = (quad ^ (l15 & 3)) * 8;
#pragma unroll
        for (int pt = 0; pt < 4; pt++)
            af[pt] = *(const bf16x8*)&As[buf][(wm * 64 + pt * 16 + l15) * 32 + slot];
#pragma unroll
        for (int ot = 0; ot < 4; ot++)
            bw[ot] = *(const bf16x8*)&Bs[buf][(wn * 64 + ot * 16 + l15) * 32 + slot];
#pragma unroll
        for (int pt = 0; pt < 4; pt++)
#pragma unroll
            for (int ot = 0; ot < 4; ot++)
                acc[pt][ot] = __builtin_amdgcn_mfma_f32_16x16x32_bf16(af[pt], bw[ot], acc[pt][ot], 0, 0, 0);
        __syncthreads();
    }

    int pw0 = p0 + wm * 64, ow0 = o0 + wn * 64;
    if (MODE == 2) {
        int isbf = *flagp;
#pragma unroll
        for (int ot = 0; ot < 4; ot++) {
            int o = ow0 + ot * 16 + l15;
            float bv = ldf(bias, o, isbf);
#pragma unroll
            for (int pt = 0; pt < 4; pt++) {
                int p = pw0 + pt * 16 + quad * 4;
                size_t idx = ((size_t)b * O + o) * P + p;
                if (!isbf) {
                    float4 v4 = {acc[pt][ot][0] + bv, acc[pt][ot][1] + bv,
                                 acc[pt][ot][2] + bv, acc[pt][ot][3] + bv};
                    *(float4*)((float*)out0 + idx) = v4;
                } else {
                    ushort4 u4 = {f2bu(acc[pt][ot][0] + bv), f2bu(acc[pt][ot][1] + bv),
                                  f2bu(acc[pt][ot][2] + bv), f2bu(acc[pt][ot][3] + bv)};
                    *(ushort4*)((bf16*)out0 + idx) = u4;
                }
            }
        }
    } else if (MODE == 0) {
#pragma unroll
        for (int ot = 0; ot < 4; ot++) {
            int o = ow0 + ot * 16 + l15;
            int h = o >> 6, d = o & 63;
            bf16* base = (bf16*)out0 + ((size_t)(b * HEADS + h) * P) * 64 + d;
#pragma unroll
            for (int pt = 0; pt < 4; pt++)
#pragma unroll
                for (int r = 0; r < 4; r++)
                    base[(size_t)(pw0 + pt * 16 + quad * 4 + r) * 64] = f2b(acc[pt][ot][r]);
        }
    } else {  // MODE 1: K | V fused
#pragma unroll
        for (int ot = 0; ot < 4; ot++) {
            int o = ow0 + ot * 16 + l15;
            if (o < INNER) {
                int h = o >> 6, d = o & 63;
                bf16* base = (bf16*)out0 + ((size_t)(b * HEADS + h) * P) * 64 + d;
#pragma unroll
                for (int pt = 0; pt < 4; pt++)
#pragma unroll
                    for (int r = 0; r < 4; r++)
                        base[(size_t)(pw0 + pt * 16 + quad * 4 + r) * 64] = f2b(acc[pt][ot][r]);
            } else {
                int ch = o - INNER;
                bf16* base = out1 + ((size_t)b * INNER + ch) * PKV;
#pragma unroll
                for (int pt = 0; pt < 4; pt++)
#pragma unroll
                    for (int r = 0; r < 4; r++)
                        base[pw0 + pt * 16 + quad * 4 + r] = f2b(acc[pt][ot][r]);
            }
        }
    }
}

// ---------------- fused MFMA attention, LDS-staged K/V via DMA -------------------
// K staged swizzled (rows 128B, slot = c^(j&7)); V staged swizzled (rows 512B,
// slot = c^(d&15)); P aliases K region after barrier. out: ao[b][p][h*64+d]
__global__ __launch_bounds__(256, 2) void attn_kernel(
        const bf16* __restrict__ qalt, const bf16* __restrict__ kalt,
        const bf16* __restrict__ valt, bf16* __restrict__ ao) {
    __shared__ __align__(16) bf16 Kl[16384];        // 32 KB; becomes P after barrier 2
    __shared__ __align__(16) bf16 Vl[16384];        // 32 KB
    __shared__ __align__(16) ushort Ot[4][16][80];  // 10 KB
    int tid = threadIdx.x;
    int wave = tid >> 6, lane = tid & 63;
    int l15 = lane & 15, quad = lane >> 4;
    int blk = blockIdx.x;
    int hg = blk % (32 * HEADS);
    int tile = blk / (32 * HEADS);
    int b = hg / HEADS;
    int h = hg % HEADS;
    int p0 = tile * 64 + wave * 16;

    const bf16* qbase = qalt + (size_t)(b * HEADS + h) * PQ * DH;
    const bf16* kbase = kalt + (size_t)(b * HEADS + h) * PKV * DH;
    const bf16* vbase = valt + ((size_t)b * INNER + h * DH) * PKV;

    // Q frags (direct per-lane loads)
    const bf16* qrow = qbase + (size_t)(p0 + l15) * DH + quad * 8;
    bf16x8 a0 = *(const bf16x8*)qrow;
    bf16x8 a1 = *(const bf16x8*)(qrow + 32);

    // stage K: 32 issues (8/wave), 8 rows of 64 elems each
    {
        int j = (lane >> 3);       // row within issue group
        int cs = lane & 7;
#pragma unroll
        for (int it = 0; it < 8; it++) {
            int jb = (wave * 8 + it) * 8;
            int jr = jb + j;
            int g = cs ^ (jr & 7);
            dma16(kbase + (size_t)jr * 64 + g * 8, &Kl[(size_t)(wave * 8 + it) * 512]);
        }
        // stage V: 32 issues (8/wave), 2 rows of 256 elems each
        int d = (lane >> 5);
        int cs2 = lane & 31;
#pragma unroll
        for (int it = 0; it < 8; it++) {
            int db = (wave * 8 + it) * 2;
            int dr = db + d;
            int g = cs2 ^ (dr & 15);
            dma16(vbase + (size_t)dr * 256 + g * 8, &Vl[(size_t)(wave * 8 + it) * 512]);
        }
    }
    __syncthreads();  // drains DMA (vmcnt) + cross-wave staging visibility

    // S = Q K^T from LDS
    floatx4 s[16];
#pragma unroll
    for (int jt = 0; jt < 16; jt++) s[jt] = (floatx4){0.f, 0.f, 0.f, 0.f};
#pragma unroll
    for (int jt = 0; jt < 16; jt++) {
        int j = jt * 16 + l15;
        bf16x8 b0 = *(const bf16x8*)&Kl[j * 64 + (quad ^ (j & 7)) * 8];
        bf16x8 b1 = *(const bf16x8*)&Kl[j * 64 + ((4 + quad) ^ (j & 7)) * 8];
        s[jt] = __builtin_amdgcn_mfma_f32_16x16x32_bf16(a0, b0, s[jt], 0, 0, 0);
        s[jt] = __builtin_amdgcn_mfma_f32_16x16x32_bf16(a1, b1, s[jt], 0, 0, 0);
    }

    // softmax (in registers)
    float pinv[4];
#pragma unroll
    for (int r = 0; r < 4; r++) {
        float mx = s[0][r];
#pragma unroll
        for (int jt = 1; jt < 16; jt++) mx = fmaxf(mx, s[jt][r]);
#pragma unroll
        for (int off = 1; off <= 8; off <<= 1) mx = fmaxf(mx, __shfl_xor(mx, off, 64));
        float sm = 0.f;
#pragma unroll
        for (int jt = 0; jt < 16; jt++) {
            float e = __expf((s[jt][r] - mx) * ATTN_SCALE);
            s[jt][r] = e;
            sm += e;
        }
#pragma unroll
        for (int off = 1; off <= 8; off <<= 1) sm += __shfl_xor(sm, off, 64);
        pinv[r] = 1.f / sm;
    }
    __syncthreads();  // all waves done reading Kl -> safe to overwrite with P

    // P (bf16) into Kl region, swizzled rows 512B: slot = c ^ row
    ushort* Plw = (ushort*)&Kl[wave * 4096];
#pragma unroll
    for (int r = 0; r < 4; r++) {
        int row = quad * 4 + r;
#pragma unroll
        for (int jt = 0; jt < 16; jt++) {
            int c = jt * 2 + (l15 >> 3);
            Plw[row * 256 + (c ^ row) * 8 + (l15 & 7)] = f2bu(s[jt][r] * pinv[r]);
        }
    }
    // P A-frags (wave-local; lgkmcnt orders write->read)
    bf16x8 pa[8];
#pragma unroll
    for (int kk = 0; kk < 8; kk++)
        pa[kk] = *(const bf16x8*)&Plw[l15 * 256 + ((kk * 4 + quad) ^ l15) * 8];

    // O = P V from LDS
    floatx4 oacc[4];
#pragma unroll
    for (int nt = 0; nt < 4; nt++) oacc[nt] = (floatx4){0.f, 0.f, 0.f, 0.f};
#pragma unroll
    for (int nt = 0; nt < 4; nt++) {
        int d = nt * 16 + l15;
#pragma unroll
        for (int kk = 0; kk < 8; kk++) {
            bf16x8 bv = *(const bf16x8*)&Vl[d * 256 + ((kk * 4 + quad) ^ l15) * 8];
            oacc[nt] = __builtin_amdgcn_mfma_f32_16x16x32_bf16(pa[kk], bv, oacc[nt], 0, 0, 0);
        }
    }

    // C-layout -> LDS -> coalesced [p][c] store
#pragma unroll
    for (int nt = 0; nt < 4; nt++)
#pragma unroll
        for (int r = 0; r < 4; r++)
            Ot[wave][quad * 4 + r][nt * 16 + l15] = f2bu(oacc[nt][r]);
    int row = lane >> 2, d0 = (lane & 3) * 16;
    uint4 ld0 = *(const uint4*)&Ot[wave][row][d0];
    uint4 ld1 = *(const uint4*)&Ot[wave][row][d0 + 8];
    bf16* dst = ao + ((size_t)b * PQ + p0 + row) * INNER + h * DH + d0;
    *(uint4*)dst = ld0;
    *(uint4*)(dst + 8) = ld1;
}

extern "C" void kernel_launch(void* const* d_in, const int* in_sizes, int n_in,
                              void* d_out, int out_size, void* d_ws, size_t ws_size,
                              hipStream_t stream) {
    const void* x        = d_in[0];
    const void* q_dw     = d_in[1];
    const void* q_gamma  = d_in[2];
    const void* q_beta   = d_in[3];
    const void* q_mean   = d_in[4];
    const void* q_var    = d_in[5];
    const void* q_pw     = d_in[6];
    const void* kv_dw    = d_in[7];
    const void* kv_gamma = d_in[8];
    const void* kv_beta  = d_in[9];
    const void* kv_mean  = d_in[10];
    const void* kv_var   = d_in[11];
    const void* kv_pw    = d_in[12];
    const void* out_w    = d_in[13];
    const void* out_b    = d_in[14];

    int* flag = (int*)d_ws;
    bf16* pool = (bf16*)((char*)d_ws + 256);
    bf16* yqt  = pool;                              // [32,1024,384] Y^T Q-path; reused as aob
    bf16* ykvt = yqt  + (size_t)32 * 1024 * 384;    // [32,256,384]  Y^T KV-path
    bf16* qalt = ykvt + (size_t)32 * 256 * 384;     // [32,6,1024,64]
    bf16* kalt = qalt + (size_t)32 * 6 * 1024 * 64; // [32,6,256,64]
    bf16* valt = kalt + (size_t)32 * 6 * 256 * 64;  // [32,384,256]
    bf16* wbf  = valt + (size_t)32 * 384 * 256;     // q_pw | kv_pw | out_w bf16
    bf16* qpw_bf = wbf;
    bf16* kvpw_bf = wbf + (size_t)INNER * CIN;
    bf16* outw_bf = kvpw_bf + (size_t)2 * INNER * CIN;
    bf16* aob  = yqt;  // alias: yqt dead after Q pointwise; attn writes [b][p][c]

    detect_kernel<<<1, 64, 0, stream>>>((const unsigned int*)x, flag);
    wconv_kernel<<<576, 256, 0, stream>>>(q_pw, kv_pw, out_w, wbf, flag);
    dw_bn_kernel<1, 32, 32><<<dim3(4, 12, 32), 256, 0, stream>>>(x, q_dw, q_gamma, q_beta, q_mean, q_var, yqt, flag);
    dw_bn_kernel<2, 16, 16><<<dim3(2, 12, 32), 256, 0, stream>>>(x, kv_dw, kv_gamma, kv_beta, kv_mean, kv_var, ykvt, flag);
    mfma_pw<1024, 0><<<dim3(8, 3, 32), 256, 0, stream>>>(qpw_bf, yqt, nullptr, qalt, nullptr, INNER, flag);
    mfma_pw<256, 1><<<dim3(2, 6, 32), 256, 0, stream>>>(kvpw_bf, ykvt, nullptr, kalt, valt, 2 * INNER, flag);
    attn_kernel<<<32 * 6 * 16, 256, 0, stream>>>(qalt, kalt, valt, aob);
    mfma_pw<1024, 2><<<dim3(8, 3, 32), 256, 0, stream>>>(outw_bf, aob, out_b, d_out, nullptr, CIN, flag);
}

// Round 2
// 241.524 us; speedup vs baseline: 1.2825x; 1.0202x over previous
//
#include <hip/hip_runtime.h>
#include <hip/hip_bf16.h>

#define CIN 384
#define PQ 1024
#define PKV 256
#define HEADS 6
#define DH 64
#define INNER 384
#define ATTN_SCALE 0.125f

typedef __hip_bfloat16 bf16;
typedef unsigned short ushort;
typedef __bf16 bf16x8 __attribute__((ext_vector_type(8)));
typedef float floatx4 __attribute__((ext_vector_type(4)));
typedef short shortx4 __attribute__((ext_vector_type(4)));

#if __has_builtin(__builtin_amdgcn_mfma_f32_16x16x16bf16_1k)
#define HAVE_MFMA16 1
#endif

__device__ __forceinline__ float b2f(bf16 v) { return __bfloat162float(v); }
__device__ __forceinline__ bf16 f2b(float v) { return __float2bfloat16(v); }
__device__ __forceinline__ ushort f2bu(float v) { bf16 h = __float2bfloat16(v); return *(ushort*)&h; }
__device__ __forceinline__ float ldf(const void* p, size_t i, int isbf) {
    return isbf ? __bfloat162float(((const bf16*)p)[i]) : ((const float*)p)[i];
}
// async global->LDS DMA, 16B per lane; LDS dest = uniform base + lane*16
__device__ __forceinline__ void dma16(const bf16* g, bf16* l) {
    __builtin_amdgcn_global_load_lds(
        (const __attribute__((address_space(1))) unsigned int*)g,
        (__attribute__((address_space(3))) unsigned int*)l, 16, 0, 0);
}

// ---------------- input dtype probe ----------------------------------------------
__global__ void detect_kernel(const unsigned int* __restrict__ x, int* __restrict__ flag) {
    if (threadIdx.x == 0 && blockIdx.x == 0) {
        int cnt = 0;
        for (int i = 0; i < 64; i++) {
            unsigned int e = (x[i] >> 7) & 0xFFu;
            if (e >= 100u && e <= 140u) cnt++;
        }
        *flag = (cnt >= 48) ? 1 : 0;
    }
}

// ---------------- weight convert: 3 segments -> contiguous bf16 ------------------
__global__ void wconv_kernel(const void* __restrict__ w0, const void* __restrict__ w1,
                             const void* __restrict__ w2, bf16* __restrict__ dst,
                             const int* __restrict__ flagp) {
    int isbf = *flagp;
    const int n0 = INNER * CIN, n1 = 2 * INNER * CIN, n2 = INNER * CIN;
    int i = blockIdx.x * 256 + threadIdx.x;
    int total = n0 + n1 + n2;
    for (; i < total; i += gridDim.x * 256) {
        float v;
        if (i < n0) v = ldf(w0, i, isbf);
        else if (i < n0 + n1) v = ldf(w1, i - n0, isbf);
        else v = ldf(w2, i - n0 - n1, isbf);
        dst[i] = f2b(v);
    }
}

// ---------------- depthwise 3x3 + BN -> Y^T [b][p][c] ----------------------------
// 16B global loads -> zero-padded LDS tile (RL=37) -> sliding-window 3x3 in
// registers -> bf16 restage through LDS (union) -> uint4 coalesced stores.
template <int STRIDE, int HO, int WO>
__global__ __launch_bounds__(256) void dw_bn_kernel(
        const void* __restrict__ x, const void* __restrict__ wdw,
        const void* __restrict__ gamma, const void* __restrict__ beta,
        const void* __restrict__ mean, const void* __restrict__ var,
        bf16* __restrict__ yt, const int* __restrict__ flagp) {
    constexpr int IN_ROWS = (8 - 1) * STRIDE + 3;       // 10 or 17
    constexpr int RL = 37;                              // slab stride 370%32=18 -> 2-way
    constexpr int PT = 8 * WO;                          // output pixels per block
    constexpr unsigned XSZ = 32u * IN_ROWS * RL * 4;
    constexpr unsigned OSZ = (unsigned)PT * 40 * 2;
    __shared__ __align__(16) char smem[XSZ > OSZ ? XSZ : OSZ];
    float (*xin)[IN_ROWS][RL] = (float (*)[IN_ROWS][RL])smem;  // [cc][i][1+w], 0/33 zero pad
    ushort (*outt)[40] = (ushort (*)[40])smem;                 // [g*WO+wo][cc]

    int isbf = *flagp;
    int rg = blockIdx.x;
    int c0 = blockIdx.y * 32;
    int b  = blockIdx.z;
    int tid = threadIdx.x;
    int ri0 = rg * 8 * STRIDE - 1;

    for (int e = tid; e < 32 * IN_ROWS; e += 256) {
        int i = e % IN_ROWS, cc = e / IN_ROWS;
        xin[cc][i][0] = 0.f;
        xin[cc][i][33] = 0.f;
    }

    const int NCHUNK = 32 * IN_ROWS * 4;
    for (int ch = tid; ch < NCHUNK; ch += 256) {
        int wc = ch & 3;
        int t  = ch >> 2;
        int i  = t % IN_ROWS;
        int cc = t / IN_ROWS;
        int row = ri0 + i;
        float f[8];
        if (row >= 0 && row < 32) {
            size_t goff = ((size_t)(b * CIN + c0 + cc) * 32 + row) * 32 + wc * 8;
            if (isbf) {
                uint4 v = *(const uint4*)((const bf16*)x + goff);
                const ushort* u = (const ushort*)&v;
#pragma unroll
                for (int j = 0; j < 8; j++) f[j] = __uint_as_float((unsigned)u[j] << 16);
            } else {
                float4 v0 = *(const float4*)((const float*)x + goff);
                float4 v1 = *(const float4*)((const float*)x + goff + 4);
                f[0] = v0.x; f[1] = v0.y; f[2] = v0.z; f[3] = v0.w;
                f[4] = v1.x; f[5] = v1.y; f[6] = v1.z; f[7] = v1.w;
            }
        } else {
#pragma unroll
            for (int j = 0; j < 8; j++) f[j] = 0.f;
        }
        float* dst = &xin[cc][i][1 + wc * 8];
#pragma unroll
        for (int j = 0; j < 8; j++) dst[j] = f[j];
    }

    int cc = tid & 31;
    int g  = tid >> 5;
    int c  = c0 + cc;
    float w9[9];
#pragma unroll
    for (int k = 0; k < 9; k++) w9[k] = ldf(wdw, c * 9 + k, isbf);
    float inv  = ldf(gamma, c, isbf) * rsqrtf(ldf(var, c, isbf) + 1e-5f);
    float bias = ldf(beta, c, isbf) - ldf(mean, c, isbf) * inv;
    __syncthreads();

    const float* xr0 = xin[cc][g * STRIDE + 0];
    const float* xr1 = xin[cc][g * STRIDE + 1];
    const float* xr2 = xin[cc][g * STRIDE + 2];
    float o[WO];
    if (STRIDE == 1) {
        float a0 = xr0[0], a1 = xr0[1];
        float b0 = xr1[0], b1 = xr1[1];
        float q0 = xr2[0], q1 = xr2[1];
#pragma unroll
        for (int wo = 0; wo < WO; wo++) {
            float a2 = xr0[wo + 2], b2 = xr1[wo + 2], q2 = xr2[wo + 2];
            float acc = w9[0] * a0 + w9[1] * a1 + w9[2] * a2
                      + w9[3] * b0 + w9[4] * b1 + w9[5] * b2
                      + w9[6] * q0 + w9[7] * q1 + w9[8] * q2;
            o[wo] = acc * inv + bias;
            a0 = a1; a1 = a2; b0 = b1; b1 = b2; q0 = q1; q1 = q2;
        }
    } else {
        float a0 = xr0[0], b0 = xr1[0], q0 = xr2[0];
#pragma unroll
        for (int wo = 0; wo < WO; wo++) {
            float a1 = xr0[2 * wo + 1], a2 = xr0[2 * wo + 2];
            float b1 = xr1[2 * wo + 1], b2 = xr1[2 * wo + 2];
            float q1 = xr2[2 * wo + 1], q2 = xr2[2 * wo + 2];
            float acc = w9[0] * a0 + w9[1] * a1 + w9[2] * a2
                      + w9[3] * b0 + w9[4] * b1 + w9[5] * b2
                      + w9[6] * q0 + w9[7] * q1 + w9[8] * q2;
            o[wo] = acc * inv + bias;
            a0 = a2; b0 = b2; q0 = q2;
        }
    }
    __syncthreads();

#pragma unroll
    for (int wo = 0; wo < WO; wo++) outt[g * WO + wo][cc] = f2bu(o[wo]);
    __syncthreads();

    const size_t pbase = (size_t)b * (HO * WO) + (size_t)rg * 8 * WO;
    for (int chk = tid; chk < PT * 4; chk += 256) {
        int k = chk & 3, p = chk >> 2;
        uint4 v = *(const uint4*)&outt[p][k * 8];
        *(uint4*)(yt + (pbase + p) * CIN + c0 + k * 8) = v;
    }
}

// ---------------- MFMA pointwise GEMM, m97-style LDS-staged, double-buffered -----
// C^T[p][o] = sum_c Yt[b][p][c] * W[o][c]. 128x128 tile, BK=32.
template <int P, int MODE>
__global__ __launch_bounds__(256, 2) void mfma_pw(
        const bf16* __restrict__ wt, const bf16* __restrict__ yt,
        const void* __restrict__ bias, void* __restrict__ out0,
        bf16* __restrict__ out1, int O, const int* __restrict__ flagp) {
    __shared__ __align__(16) bf16 As[2][4096];  // 128 rows x 32 k
    __shared__ __align__(16) bf16 Bs[2][4096];
    int tid = threadIdx.x;
    int wave = tid >> 6, lane = tid & 63;
    int l15 = lane & 15, quad = lane >> 4;
    int wm = wave & 1, wn = wave >> 1;
    int b = blockIdx.z;
    int p0 = blockIdx.x * 128;
    int o0 = blockIdx.y * 128;

    const bf16* asrc = yt + ((size_t)b * P + p0) * CIN;
    const bf16* bsrc = wt + (size_t)o0 * CIN;

    int srow = (lane >> 2);
    int sc   = lane & 3;
    auto stage = [&](int step, int buf) {
#pragma unroll
        for (int it = 0; it < 2; it++) {
            int row = wave * 32 + it * 16 + srow;
            int g = sc ^ (row & 3);
            size_t goff = (size_t)row * CIN + step * 32 + g * 8;
            dma16(asrc + goff, &As[buf][(wave * 2 + it) * 512]);
            dma16(bsrc + goff, &Bs[buf][(wave * 2 + it) * 512]);
        }
    };

    floatx4 acc[4][4];
#pragma unroll
    for (int pt = 0; pt < 4; pt++)
#pragma unroll
        for (int ot = 0; ot < 4; ot++) acc[pt][ot] = (floatx4){0.f, 0.f, 0.f, 0.f};

    stage(0, 0);
    __syncthreads();
    for (int s = 0; s < CIN / 32; s++) {
        int buf = s & 1;
        if (s < CIN / 32 - 1) stage(s + 1, buf ^ 1);
        bf16x8 af[4], bw[4];
        int slot = (quad ^ (l15 & 3)) * 8;
#pragma unroll
        for (int pt = 0; pt < 4; pt++)
            af[pt] = *(const bf16x8*)&As[buf][(wm * 64 + pt * 16 + l15) * 32 + slot];
#pragma unroll
        for (int ot = 0; ot < 4; ot++)
            bw[ot] = *(const bf16x8*)&Bs[buf][(wn * 64 + ot * 16 + l15) * 32 + slot];
#pragma unroll
        for (int pt = 0; pt < 4; pt++)
#pragma unroll
            for (int ot = 0; ot < 4; ot++)
                acc[pt][ot] = __builtin_amdgcn_mfma_f32_16x16x32_bf16(af[pt], bw[ot], acc[pt][ot], 0, 0, 0);
        __syncthreads();
    }

    int pw0 = p0 + wm * 64, ow0 = o0 + wn * 64;
    if (MODE == 2) {
        int isbf = *flagp;
#pragma unroll
        for (int ot = 0; ot < 4; ot++) {
            int o = ow0 + ot * 16 + l15;
            float bv = ldf(bias, o, isbf);
#pragma unroll
            for (int pt = 0; pt < 4; pt++) {
                int p = pw0 + pt * 16 + quad * 4;
                size_t idx = ((size_t)b * O + o) * P + p;
                if (!isbf) {
                    float4 v4 = {acc[pt][ot][0] + bv, acc[pt][ot][1] + bv,
                                 acc[pt][ot][2] + bv, acc[pt][ot][3] + bv};
                    *(float4*)((float*)out0 + idx) = v4;
                } else {
                    ushort4 u4 = {f2bu(acc[pt][ot][0] + bv), f2bu(acc[pt][ot][1] + bv),
                                  f2bu(acc[pt][ot][2] + bv), f2bu(acc[pt][ot][3] + bv)};
                    *(ushort4*)((bf16*)out0 + idx) = u4;
                }
            }
        }
    } else if (MODE == 0) {
#pragma unroll
        for (int ot = 0; ot < 4; ot++) {
            int o = ow0 + ot * 16 + l15;
            int h = o >> 6, d = o & 63;
            bf16* base = (bf16*)out0 + ((size_t)(b * HEADS + h) * P) * 64 + d;
#pragma unroll
            for (int pt = 0; pt < 4; pt++)
#pragma unroll
                for (int r = 0; r < 4; r++)
                    base[(size_t)(pw0 + pt * 16 + quad * 4 + r) * 64] = f2b(acc[pt][ot][r]);
        }
    } else {  // MODE 1: K | V fused
#pragma unroll
        for (int ot = 0; ot < 4; ot++) {
            int o = ow0 + ot * 16 + l15;
            if (o < INNER) {
                int h = o >> 6, d = o & 63;
                bf16* base = (bf16*)out0 + ((size_t)(b * HEADS + h) * P) * 64 + d;
#pragma unroll
                for (int pt = 0; pt < 4; pt++)
#pragma unroll
                    for (int r = 0; r < 4; r++)
                        base[(size_t)(pw0 + pt * 16 + quad * 4 + r) * 64] = f2b(acc[pt][ot][r]);
            } else {
                int ch = o - INNER;
                bf16* base = out1 + ((size_t)b * INNER + ch) * PKV;
#pragma unroll
                for (int pt = 0; pt < 4; pt++)
#pragma unroll
                    for (int r = 0; r < 4; r++)
                        base[pw0 + pt * 16 + quad * 4 + r] = f2b(acc[pt][ot][r]);
            }
        }
    }
}

// ---------------- fused MFMA attention v2: swapped QK^T, register P --------------
// Each block: one (b,h), 256 Q rows = 4 tiles of 64. K/V staged ONCE (DMA,
// swizzled), then a barrier-free tile loop. Swapped S^T = mfma(K,Q) puts P for
// q=lane&15 in-lane with k = jt*16 + quad*4 + r -- exactly the 16x16x16 A-frag
// layout, so PV consumes P straight from registers (no LDS P, no exchange).
__global__ __launch_bounds__(256, 2) void attn_kernel(
        const bf16* __restrict__ qalt, const bf16* __restrict__ kalt,
        const bf16* __restrict__ valt, bf16* __restrict__ ao) {
    __shared__ __align__(16) bf16 Kl[16384];        // 32 KB, persistent
    __shared__ __align__(16) bf16 Vl[16384];        // 32 KB, persistent
    __shared__ __align__(16) ushort Ot[4][16][80];  // 10 KB, per-wave scratch
    int tid = threadIdx.x;
    int wave = tid >> 6, lane = tid & 63;
    int l15 = lane & 15, quad = lane >> 4;
    int blk = blockIdx.x;
    int swz = (blk & 7) * 96 + (blk >> 3);   // XCD-chunked (768 = 8*96, bijective)
    int seg = swz & 3;                        // 4 row-segments of 256
    int bh  = swz >> 2;
    int b = bh / HEADS, h = bh % HEADS;

    const bf16* qbase = qalt + (size_t)(b * HEADS + h) * PQ * DH;
    const bf16* kbase = kalt + (size_t)(b * HEADS + h) * PKV * DH;
    const bf16* vbase = valt + ((size_t)b * INNER + h * DH) * PKV;

    // stage K: rows 128B, granule slot = c ^ (row&7)
    {
        int j = lane >> 3, cs = lane & 7;
#pragma unroll
        for (int it = 0; it < 8; it++) {
            int jr = (wave * 8 + it) * 8 + j;
            int g = cs ^ (jr & 7);
            dma16(kbase + (size_t)jr * 64 + g * 8, &Kl[(wave * 8 + it) * 512]);
        }
        // stage V: rows 512B, granule slot = c ^ (row&15)
        int d = lane >> 5, cs2 = lane & 31;
#pragma unroll
        for (int it = 0; it < 8; it++) {
            int dr = (wave * 8 + it) * 2 + d;
            int g = cs2 ^ (dr & 15);
            dma16(vbase + (size_t)dr * 256 + g * 8, &Vl[(wave * 8 + it) * 512]);
        }
    }

    int p0 = seg * 256 + wave * 16;  // tile t adds t*64
    const bf16* qrow = qbase + (size_t)(p0 + l15) * DH + quad * 8;
    bf16x8 qc0 = *(const bf16x8*)qrow;          // overlaps the K/V DMA
    bf16x8 qc1 = *(const bf16x8*)(qrow + 32);
    __syncthreads();  // drains DMA (vmcnt) + cross-wave staging visibility

#pragma unroll
    for (int t = 0; t < 4; t++) {
        // prefetch next tile's Q under this tile's compute
        bf16x8 qn0 = qc0, qn1 = qc1;
        if (t < 3) {
            const bf16* qr = qrow + (size_t)(t + 1) * 64 * DH;
            qn0 = *(const bf16x8*)qr;
            qn1 = *(const bf16x8*)(qr + 32);
        }

        // S^T = K Q^T : lane holds S[q=l15][k = jt*16 + quad*4 + r]
        floatx4 s[16];
#pragma unroll
        for (int jt = 0; jt < 16; jt++) s[jt] = (floatx4){0.f, 0.f, 0.f, 0.f};
#pragma unroll
        for (int jt = 0; jt < 16; jt++) {
            int j = jt * 16 + l15;
            bf16x8 k0 = *(const bf16x8*)&Kl[j * 64 + (quad ^ (j & 7)) * 8];
            bf16x8 k1 = *(const bf16x8*)&Kl[j * 64 + ((4 + quad) ^ (j & 7)) * 8];
            s[jt] = __builtin_amdgcn_mfma_f32_16x16x32_bf16(k0, qc0, s[jt], 0, 0, 0);
            s[jt] = __builtin_amdgcn_mfma_f32_16x16x32_bf16(k1, qc1, s[jt], 0, 0, 0);
        }

        // softmax: row q=l15 spread over 4 quads -> 2 shuffles per reduce
        float mx = s[0][0];
#pragma unroll
        for (int jt = 0; jt < 16; jt++)
#pragma unroll
            for (int r = 0; r < 4; r++) mx = fmaxf(mx, s[jt][r]);
        mx = fmaxf(mx, __shfl_xor(mx, 16, 64));
        mx = fmaxf(mx, __shfl_xor(mx, 32, 64));
        float sm = 0.f;
#pragma unroll
        for (int jt = 0; jt < 16; jt++)
#pragma unroll
            for (int r = 0; r < 4; r++) {
                float e = __expf((s[jt][r] - mx) * ATTN_SCALE);
                s[jt][r] = e;
                sm += e;
            }
        sm += __shfl_xor(sm, 16, 64);
        sm += __shfl_xor(sm, 32, 64);
        float pinv = 1.f / sm;

        // O = P V
        floatx4 oacc[4];
#pragma unroll
        for (int nt = 0; nt < 4; nt++) oacc[nt] = (floatx4){0.f, 0.f, 0.f, 0.f};
#ifdef HAVE_MFMA16
#pragma unroll
        for (int jt = 0; jt < 16; jt++) {
            shortx4 pa;
#pragma unroll
            for (int r = 0; r < 4; r++) pa[r] = (short)f2bu(s[jt][r] * pinv);
#pragma unroll
            for (int nt = 0; nt < 4; nt++) {
                int d = nt * 16 + l15;
                shortx4 bv = *(const shortx4*)&Vl[d * 256 +
                        ((jt * 2 + (quad >> 1)) ^ (d & 15)) * 8 + (quad & 1) * 4];
                oacc[nt] = __builtin_amdgcn_mfma_f32_16x16x16bf16_1k(pa, bv, oacc[nt], 0, 0, 0);
            }
        }
#else
        // fallback: assemble 16x16x32 A-frags via in-wave shuffles
#pragma unroll
        for (int kk = 0; kk < 8; kk++) {
            unsigned Ad0 = ((unsigned)f2bu(s[2 * kk][1] * pinv) << 16) | f2bu(s[2 * kk][0] * pinv);
            unsigned Ad1 = ((unsigned)f2bu(s[2 * kk][3] * pinv) << 16) | f2bu(s[2 * kk][2] * pinv);
            unsigned Bd0 = ((unsigned)f2bu(s[2 * kk + 1][1] * pinv) << 16) | f2bu(s[2 * kk + 1][0] * pinv);
            unsigned Bd1 = ((unsigned)f2bu(s[2 * kk + 1][3] * pinv) << 16) | f2bu(s[2 * kk + 1][2] * pinv);
            int srcA = l15 + ((quad & 1) << 5);
            unsigned dw[4];
#pragma unroll
            for (int i = 0; i < 4; i++) {
                int srcl = srcA + ((i >> 1) << 4);
                unsigned ta = (i & 1) ? __shfl((int)Ad1, srcl, 64) : __shfl((int)Ad0, srcl, 64);
                unsigned tb = (i & 1) ? __shfl((int)Bd1, srcl, 64) : __shfl((int)Bd0, srcl, 64);
                dw[i] = (quad >> 1) ? tb : ta;
            }
            union { unsigned u[4]; bf16x8 v; } pc;
            pc.u[0] = dw[0]; pc.u[1] = dw[1]; pc.u[2] = dw[2]; pc.u[3] = dw[3];
#pragma unroll
            for (int nt = 0; nt < 4; nt++) {
                int d = nt * 16 + l15;
                bf16x8 bv = *(const bf16x8*)&Vl[d * 256 + ((kk * 4 + quad) ^ (d & 15)) * 8];
                oacc[nt] = __builtin_amdgcn_mfma_f32_16x16x32_bf16(pc.v, bv, oacc[nt], 0, 0, 0);
            }
        }
#endif

        // C-layout -> per-wave LDS slice -> coalesced [p][c] store (wave-local)
#pragma unroll
        for (int nt = 0; nt < 4; nt++)
#pragma unroll
            for (int r = 0; r < 4; r++)
                Ot[wave][quad * 4 + r][nt * 16 + l15] = f2bu(oacc[nt][r]);
        int row = lane >> 2, d0 = (lane & 3) * 16;
        uint4 ld0 = *(const uint4*)&Ot[wave][row][d0];
        uint4 ld1 = *(const uint4*)&Ot[wave][row][d0 + 8];
        bf16* dst = ao + ((size_t)b * PQ + p0 + t * 64 + row) * INNER + h * DH + d0;
        *(uint4*)dst = ld0;
        *(uint4*)(dst + 8) = ld1;

        qc0 = qn0; qc1 = qn1;
    }
}

extern "C" void kernel_launch(void* const* d_in, const int* in_sizes, int n_in,
                              void* d_out, int out_size, void* d_ws, size_t ws_size,
                              hipStream_t stream) {
    const void* x        = d_in[0];
    const void* q_dw     = d_in[1];
    const void* q_gamma  = d_in[2];
    const void* q_beta   = d_in[3];
    const void* q_mean   = d_in[4];
    const void* q_var    = d_in[5];
    const void* q_pw     = d_in[6];
    const void* kv_dw    = d_in[7];
    const void* kv_gamma = d_in[8];
    const void* kv_beta  = d_in[9];
    const void* kv_mean  = d_in[10];
    const void* kv_var   = d_in[11];
    const void* kv_pw    = d_in[12];
    const void* out_w    = d_in[13];
    const void* out_b    = d_in[14];

    int* flag = (int*)d_ws;
    bf16* pool = (bf16*)((char*)d_ws + 256);
    bf16* yqt  = pool;                              // [32,1024,384] Y^T Q-path; reused as aob
    bf16* ykvt = yqt  + (size_t)32 * 1024 * 384;    // [32,256,384]  Y^T KV-path
    bf16* qalt = ykvt + (size_t)32 * 256 * 384;     // [32,6,1024,64]
    bf16* kalt = qalt + (size_t)32 * 6 * 1024 * 64; // [32,6,256,64]
    bf16* valt = kalt + (size_t)32 * 6 * 256 * 64;  // [32,384,256]
    bf16* wbf  = valt + (size_t)32 * 384 * 256;     // q_pw | kv_pw | out_w bf16
    bf16* qpw_bf = wbf;
    bf16* kvpw_bf = wbf + (size_t)INNER * CIN;
    bf16* outw_bf = kvpw_bf + (size_t)2 * INNER * CIN;
    bf16* aob  = yqt;  // alias: yqt dead after Q pointwise; attn writes [b][p][c]

    detect_kernel<<<1, 64, 0, stream>>>((const unsigned int*)x, flag);
    wconv_kernel<<<576, 256, 0, stream>>>(q_pw, kv_pw, out_w, wbf, flag);
    dw_bn_kernel<1, 32, 32><<<dim3(4, 12, 32), 256, 0, stream>>>(x, q_dw, q_gamma, q_beta, q_mean, q_var, yqt, flag);
    dw_bn_kernel<2, 16, 16><<<dim3(2, 12, 32), 256, 0, stream>>>(x, kv_dw, kv_gamma, kv_beta, kv_mean, kv_var, ykvt, flag);
    mfma_pw<1024, 0><<<dim3(8, 3, 32), 256, 0, stream>>>(qpw_bf, yqt, nullptr, qalt, nullptr, INNER, flag);
    mfma_pw<256, 1><<<dim3(2, 6, 32), 256, 0, stream>>>(kvpw_bf, ykvt, nullptr, kalt, valt, 2 * INNER, flag);
    attn_kernel<<<768, 256, 0, stream>>>(qalt, kalt, valt, aob);
    mfma_pw<1024, 2><<<dim3(8, 3, 32), 256, 0, stream>>>(outw_bf, aob, out_b, d_out, nullptr, CIN, flag);
}